// Round 1
// baseline (1001.593 us; speedup 1.0000x reference)
//
#include <hip/hip_runtime.h>
#include <math.h>

// ---------------------------------------------------------------------------
// 3-layer GAT on MI355X. Round 0: correctness-first fp32 implementation.
//   N=50000 nodes, E=400000 edges, layers: 64->4x128 -> 512->4x128 -> 512->128
// Pipeline per launch:
//   CSR build (counts -> scan -> fill), then per layer:
//     GEMM (LDS-tiled fp32) -> alpha_s/alpha_d dots -> segment-softmax+aggregate
// ---------------------------------------------------------------------------

#define LRELU_SLOPE 0.2f

// ---------------- CSR build ----------------

__global__ void count_deg_kernel(const int* __restrict__ dst, int* __restrict__ counts, int E) {
    int e = blockIdx.x * blockDim.x + threadIdx.x;
    if (e < E) atomicAdd(&counts[dst[e]], 1);
}

__global__ __launch_bounds__(1024) void scan_kernel(const int* __restrict__ counts,
                                                    int* __restrict__ row_ptr, int n) {
    __shared__ int sdata[1024];
    __shared__ int s_carry;
    if (threadIdx.x == 0) { s_carry = 0; row_ptr[0] = 0; }
    __syncthreads();
    for (int base = 0; base < n; base += 1024) {
        int i = base + (int)threadIdx.x;
        int v = (i < n) ? counts[i] : 0;
        sdata[threadIdx.x] = v;
        __syncthreads();
        for (int off = 1; off < 1024; off <<= 1) {
            int t = 0;
            if ((int)threadIdx.x >= off) t = sdata[threadIdx.x - off];
            __syncthreads();
            sdata[threadIdx.x] += t;
            __syncthreads();
        }
        int inc = sdata[threadIdx.x] + s_carry;
        if (i < n) row_ptr[i + 1] = inc;
        __syncthreads();
        if (threadIdx.x == 1023) s_carry = inc;
        __syncthreads();
    }
}

__global__ void init_cursor_kernel(const int* __restrict__ row_ptr, int* __restrict__ cursor, int n) {
    int i = blockIdx.x * blockDim.x + threadIdx.x;
    if (i < n) cursor[i] = row_ptr[i];
}

__global__ void fill_csr_kernel(const int* __restrict__ src, const int* __restrict__ dst,
                                int* __restrict__ cursor, int* __restrict__ csr_src, int E) {
    int e = blockIdx.x * blockDim.x + threadIdx.x;
    if (e < E) {
        int d = dst[e];
        int pos = atomicAdd(&cursor[d], 1);
        csr_src[pos] = src[e];
    }
}

// ---------------- GEMM: C[M,N] = A[M,K] @ B[K,N], fp32, row-major ----------
// BM=BN=64, BK=16, 256 threads, 4x4 micro-tile. N,K multiples of {64,16}; M guarded.

#define BM 64
#define BN 64
#define BK 16

__global__ __launch_bounds__(256) void gemm_kernel(const float* __restrict__ A,
                                                   const float* __restrict__ B,
                                                   float* __restrict__ C,
                                                   int M, int N, int K) {
    __shared__ float As[BK][BM + 4];
    __shared__ float Bs[BK][BN + 4];
    const int tid = threadIdx.x;
    const int tx = tid % 16;       // col group
    const int ty = tid / 16;       // row group
    const int rowBase = blockIdx.y * BM;
    const int colBase = blockIdx.x * BN;

    float acc[4][4] = {};

    const int aRow = tid / 4;            // 0..63
    const int aK4  = (tid % 4) * 4;      // 0,4,8,12
    const int bK   = tid / 16;           // 0..15
    const int bC4  = (tid % 16) * 4;     // 0..60

    for (int k0 = 0; k0 < K; k0 += BK) {
        int gr = rowBase + aRow;
        float4 a4 = {0.f, 0.f, 0.f, 0.f};
        if (gr < M)
            a4 = *reinterpret_cast<const float4*>(&A[(size_t)gr * K + k0 + aK4]);
        As[aK4 + 0][aRow] = a4.x;
        As[aK4 + 1][aRow] = a4.y;
        As[aK4 + 2][aRow] = a4.z;
        As[aK4 + 3][aRow] = a4.w;

        float4 b4 = *reinterpret_cast<const float4*>(&B[(size_t)(k0 + bK) * N + colBase + bC4]);
        *reinterpret_cast<float4*>(&Bs[bK][bC4]) = b4;

        __syncthreads();
        #pragma unroll
        for (int kk = 0; kk < BK; ++kk) {
            float4 av = *reinterpret_cast<const float4*>(&As[kk][ty * 4]);
            float4 bv = *reinterpret_cast<const float4*>(&Bs[kk][tx * 4]);
            float ar[4] = {av.x, av.y, av.z, av.w};
            float br[4] = {bv.x, bv.y, bv.z, bv.w};
            #pragma unroll
            for (int i = 0; i < 4; ++i)
                #pragma unroll
                for (int j = 0; j < 4; ++j)
                    acc[i][j] += ar[i] * br[j];
        }
        __syncthreads();
    }

    #pragma unroll
    for (int i = 0; i < 4; ++i) {
        int gr = rowBase + ty * 4 + i;
        if (gr < M) {
            #pragma unroll
            for (int j = 0; j < 4; ++j)
                C[(size_t)gr * N + colBase + tx * 4 + j] = acc[i][j];
        }
    }
}

// ---------------- alpha_s / alpha_d: per-node per-head dots ----------------
// One wave per node; lane l owns HC/64 consecutive channels.

template <int H, int C>
__global__ __launch_bounds__(256) void alphas_kernel(const float* __restrict__ h,
                                                     const float* __restrict__ a_src,
                                                     const float* __restrict__ a_dst,
                                                     float* __restrict__ als,
                                                     float* __restrict__ ald,
                                                     int n_nodes) {
    constexpr int HC  = H * C;
    constexpr int PER = HC / 64;   // elems per lane
    constexpr int GRP = 64 / H;    // lanes per head
    const int wave = threadIdx.x / 64;
    const int lane = threadIdx.x % 64;
    const int n = blockIdx.x * (blockDim.x / 64) + wave;
    if (n >= n_nodes) return;

    const float* hr = h + (size_t)n * HC + lane * PER;
    float s_acc = 0.f, d_acc = 0.f;
    #pragma unroll
    for (int j = 0; j < PER; ++j) {
        float hv = hr[j];
        s_acc += hv * a_src[lane * PER + j];
        d_acc += hv * a_dst[lane * PER + j];
    }
    #pragma unroll
    for (int off = GRP / 2; off >= 1; off >>= 1) {
        s_acc += __shfl_xor(s_acc, off);
        d_acc += __shfl_xor(d_acc, off);
    }
    if (lane % GRP == 0) {
        int head = lane / GRP;
        als[(size_t)n * H + head] = s_acc;
        ald[(size_t)n * H + head] = d_acc;
    }
}

// ---------------- segment softmax + weighted aggregate ---------------------
// One block per dst node. Block = H*64 threads (wave w <-> head w in phase 1).
// Phase 1: per-head running max then exp-sum over incoming edges (wave shuffles).
// Phase 2: chunks of 64 edges; 64*H threads compute alpha into LDS; then each
// thread accumulates its float2 channel pair over the chunk (coalesced gather).

template <int H, int C>
__global__ __launch_bounds__(H * 64) void aggregate_kernel(const float* __restrict__ hfeat,
                                                           const float* __restrict__ als,
                                                           const float* __restrict__ ald,
                                                           const int* __restrict__ row_ptr,
                                                           const int* __restrict__ csr_src,
                                                           const float* __restrict__ bias,
                                                           float* __restrict__ out,
                                                           int n_nodes) {
    constexpr int HC = H * C;
    static_assert(C == 128, "thread mapping assumes C==128");
    const int n = blockIdx.x;
    const int t = threadIdx.x;
    const int lane = t % 64;
    const int wave = t / 64;   // = head in phase 1

    __shared__ float sm_m[H], sm_scale[H], sm_ald[H];
    __shared__ float sm_alpha[64 * H];
    __shared__ int   sm_src[64];

    const int start = row_ptr[n];
    const int deg = row_ptr[n + 1] - start;

    // ---- phase 1: softmax stats per head ----
    {
        const int h = wave;
        const float aldv = ald[(size_t)n * H + h];
        float mx = -INFINITY;
        for (int i = lane; i < deg; i += 64) {
            int s = csr_src[start + i];
            float e = als[(size_t)s * H + h] + aldv;
            e = (e > 0.f) ? e : LRELU_SLOPE * e;
            mx = fmaxf(mx, e);
        }
        #pragma unroll
        for (int off = 32; off >= 1; off >>= 1) mx = fmaxf(mx, __shfl_xor(mx, off));
        float sum = 0.f;
        for (int i = lane; i < deg; i += 64) {
            int s = csr_src[start + i];
            float e = als[(size_t)s * H + h] + aldv;
            e = (e > 0.f) ? e : LRELU_SLOPE * e;
            sum += expf(e - mx);
        }
        #pragma unroll
        for (int off = 32; off >= 1; off >>= 1) sum += __shfl_xor(sum, off);
        if (lane == 0) {
            sm_m[h] = mx;
            sm_scale[h] = 1.0f / (sum + 1e-16f);
            sm_ald[h] = aldv;
        }
    }
    __syncthreads();

    // ---- phase 2: chunked gather-accumulate ----
    float2 acc = {0.f, 0.f};
    const int c2 = 2 * t;              // channel pair (flat hc index)
    const int headc = (2 * t) / C;     // owning head

    for (int base = 0; base < deg; base += 64) {
        const int chunk = min(64, deg - base);
        {
            const int i = t & 63;      // edge within chunk
            const int h = t / 64;      // head
            if (i < chunk) {
                int s = csr_src[start + base + i];
                if (h == 0) sm_src[i] = s;
                float e = als[(size_t)s * H + h] + sm_ald[h];
                e = (e > 0.f) ? e : LRELU_SLOPE * e;
                sm_alpha[i * H + h] = expf(e - sm_m[h]) * sm_scale[h];
            }
        }
        __syncthreads();
        for (int i = 0; i < chunk; ++i) {
            const int s = sm_src[i];
            const float a = sm_alpha[i * H + headc];
            const float2 v = *reinterpret_cast<const float2*>(&hfeat[(size_t)s * HC + c2]);
            acc.x += a * v.x;
            acc.y += a * v.y;
        }
        __syncthreads();
    }

    // ---- epilogue: + bias, ELU ----
    float o0 = acc.x + bias[c2];
    float o1 = acc.y + bias[c2 + 1];
    o0 = (o0 > 0.f) ? o0 : expm1f(o0);
    o1 = (o1 > 0.f) ? o1 : expm1f(o1);
    out[(size_t)n * HC + c2]     = o0;
    out[(size_t)n * HC + c2 + 1] = o1;
}

// ---------------------------------------------------------------------------

extern "C" void kernel_launch(void* const* d_in, const int* in_sizes, int n_in,
                              void* d_out, int out_size, void* d_ws, size_t ws_size,
                              hipStream_t stream) {
    const float* x   = (const float*)d_in[0];
    const int*   ei  = (const int*)d_in[1];
    const float* W1  = (const float*)d_in[2];
    const float* as1 = (const float*)d_in[3];
    const float* ad1 = (const float*)d_in[4];
    const float* b1  = (const float*)d_in[5];
    const float* W2  = (const float*)d_in[6];
    const float* as2 = (const float*)d_in[7];
    const float* ad2 = (const float*)d_in[8];
    const float* b2  = (const float*)d_in[9];
    const float* W3  = (const float*)d_in[10];
    const float* as3 = (const float*)d_in[11];
    const float* ad3 = (const float*)d_in[12];
    const float* b3  = (const float*)d_in[13];

    const int N = in_sizes[0] / 64;      // 50000
    const int E = in_sizes[1] / 2;       // 400000
    const int HC = 512;                  // 4 heads x 128

    const int* src = ei;
    const int* dst = ei + E;

    // workspace carve-up (256B aligned)
    size_t off = 0;
    auto carve = [&](size_t bytes) -> void* {
        void* p = (char*)d_ws + off;
        off += (bytes + 255) & ~(size_t)255;
        return p;
    };
    float* h_buf    = (float*)carve((size_t)N * HC * sizeof(float));
    float* feat_buf = (float*)carve((size_t)N * HC * sizeof(float));
    float* als      = (float*)carve((size_t)N * 4 * sizeof(float));
    float* ald      = (float*)carve((size_t)N * 4 * sizeof(float));
    int*   counts   = (int*)carve((size_t)N * sizeof(int));
    int*   row_ptr  = (int*)carve((size_t)(N + 1) * sizeof(int));
    int*   cursor   = (int*)carve((size_t)N * sizeof(int));
    int*   csr_src  = (int*)carve((size_t)E * sizeof(int));
    (void)ws_size;

    // ---- CSR build ----
    hipMemsetAsync(counts, 0, (size_t)N * sizeof(int), stream);
    count_deg_kernel<<<(E + 255) / 256, 256, 0, stream>>>(dst, counts, E);
    scan_kernel<<<1, 1024, 0, stream>>>(counts, row_ptr, N);
    init_cursor_kernel<<<(N + 255) / 256, 256, 0, stream>>>(row_ptr, cursor, N);
    fill_csr_kernel<<<(E + 255) / 256, 256, 0, stream>>>(src, dst, cursor, csr_src, E);

    dim3 gemm_block(256);
    const int rowTiles = (N + BM - 1) / BM;

    // ---- layer 1: x[N,64] @ W1[64,512] ----
    {
        dim3 grid(512 / BN, rowTiles);
        gemm_kernel<<<grid, gemm_block, 0, stream>>>(x, W1, h_buf, N, 512, 64);
        alphas_kernel<4, 128><<<(N + 3) / 4, 256, 0, stream>>>(h_buf, as1, ad1, als, ald, N);
        aggregate_kernel<4, 128><<<N, 256, 0, stream>>>(h_buf, als, ald, row_ptr, csr_src,
                                                        b1, feat_buf, N);
    }
    // ---- layer 2: feat[N,512] @ W2[512,512] ----
    {
        dim3 grid(512 / BN, rowTiles);
        gemm_kernel<<<grid, gemm_block, 0, stream>>>(feat_buf, W2, h_buf, N, 512, 512);
        alphas_kernel<4, 128><<<(N + 3) / 4, 256, 0, stream>>>(h_buf, as2, ad2, als, ald, N);
        aggregate_kernel<4, 128><<<N, 256, 0, stream>>>(h_buf, als, ald, row_ptr, csr_src,
                                                        b2, feat_buf, N);
    }
    // ---- layer 3: feat[N,512] @ W3[512,128], single head ----
    {
        dim3 grid(128 / BN, rowTiles);
        gemm_kernel<<<grid, gemm_block, 0, stream>>>(feat_buf, W3, h_buf, N, 128, 512);
        alphas_kernel<1, 128><<<(N + 3) / 4, 256, 0, stream>>>(h_buf, as3, ad3, als, ald, N);
        aggregate_kernel<1, 128><<<N, 64, 0, stream>>>(h_buf, als, ald, row_ptr, csr_src,
                                                       b3, (float*)d_out, N);
    }
}

// Round 2
// 498.268 us; speedup vs baseline: 2.0101x; 2.0101x over previous
//
#include <hip/hip_runtime.h>
#include <math.h>

// ---------------------------------------------------------------------------
// 3-layer GAT on MI355X — round 2: bf16 MFMA GEMM + bf16 gathers + wave-per-node
// aggregation.  N=50000, E=400000; layers 64->4x128 -> 512->4x128 -> 512->128.
// ---------------------------------------------------------------------------

#define LRELU_SLOPE 0.2f
#define MPAD 50048              // 391 * 128, padded row count for GEMM A tiles

typedef __attribute__((ext_vector_type(8))) short short8;
typedef __attribute__((ext_vector_type(4))) float f32x4;

__device__ __forceinline__ float bf2f(unsigned short u) {
    return __uint_as_float(((unsigned int)u) << 16);
}
__device__ __forceinline__ unsigned short f2bf(float f) {
    unsigned int u = __float_as_uint(f);
    unsigned int r = u + 0x7FFFu + ((u >> 16) & 1u);   // RNE
    return (unsigned short)(r >> 16);
}
__device__ __forceinline__ void load16_to_lds(const void* g, void* l) {
    __builtin_amdgcn_global_load_lds(
        (const __attribute__((address_space(1))) void*)g,
        (__attribute__((address_space(3))) void*)l, 16, 0, 0);
}

// ---------------- CSR build ----------------

__global__ void count_deg_kernel(const int* __restrict__ dst, int* __restrict__ counts, int E) {
    int e = blockIdx.x * blockDim.x + threadIdx.x;
    if (e < E) atomicAdd(&counts[dst[e]], 1);
}

__global__ __launch_bounds__(1024) void scan_kernel(const int* __restrict__ counts,
                                                    int* __restrict__ row_ptr, int n) {
    __shared__ int warp_sums[16];
    const int CH = (n + 1023) / 1024;
    const int t = threadIdx.x;
    const int lane = t & 63, w = t >> 6;
    const int base = t * CH;
    int s = 0;
    for (int i = 0; i < CH; ++i) {
        int idx = base + i;
        if (idx < n) s += counts[idx];
    }
    int v = s;
    #pragma unroll
    for (int off = 1; off < 64; off <<= 1) {
        int u = __shfl_up(v, off);
        if (lane >= off) v += u;
    }
    if (lane == 63) warp_sums[w] = v;
    __syncthreads();
    if (t == 0) {
        int run = 0;
        #pragma unroll
        for (int i = 0; i < 16; ++i) { int tmp = warp_sums[i]; warp_sums[i] = run; run += tmp; }
        row_ptr[0] = 0;
    }
    __syncthreads();
    int run = warp_sums[w] + (v - s);   // exclusive prefix of this thread's chunk
    for (int i = 0; i < CH; ++i) {
        int idx = base + i;
        if (idx < n) { run += counts[idx]; row_ptr[idx + 1] = run; }
    }
}

__global__ void init_cursor_kernel(const int* __restrict__ row_ptr, int* __restrict__ cursor, int n) {
    int i = blockIdx.x * blockDim.x + threadIdx.x;
    if (i < n) cursor[i] = row_ptr[i];
}

__global__ void fill_csr_kernel(const int* __restrict__ src, const int* __restrict__ dst,
                                int* __restrict__ cursor, int* __restrict__ csr_src, int E) {
    int e = blockIdx.x * blockDim.x + threadIdx.x;
    if (e < E) {
        int d = dst[e];
        int pos = atomicAdd(&cursor[d], 1);
        csr_src[pos] = src[e];
    }
}

// ---------------- casts ----------------

__global__ void cast_f32_bf16_kernel(const float* __restrict__ in, unsigned short* __restrict__ out,
                                     size_t n) {
    size_t i = (size_t)blockIdx.x * blockDim.x + threadIdx.x;
    if (i < n) out[i] = f2bf(in[i]);
}

// W [K, Nw] fp32 row-major  ->  Wt [Nw, K] bf16 row-major
__global__ void transpose_cast_kernel(const float* __restrict__ W, unsigned short* __restrict__ Wt,
                                      int K, int Nw) {
    int i = blockIdx.x * blockDim.x + threadIdx.x;
    if (i < K * Nw) {
        int k = i / Nw, nn = i % Nw;
        Wt[(size_t)nn * K + k] = f2bf(W[i]);
    }
}

// ---------------- bf16 MFMA GEMM: C[M,N] = A[Mpad,K] @ Bt[N,K]^T ------------
// 128x128 tile, BK=32, 4 waves (2x2), each wave 64x64 (4x4 frags of 16x16x32).

__global__ __launch_bounds__(256) void gemm_mfma_kernel(
    const unsigned short* __restrict__ A,    // [>=grid.y*128, K] bf16
    const unsigned short* __restrict__ Bt,   // [N, K] bf16
    unsigned short* __restrict__ C,          // [M, N] bf16
    int M, int N, int K)
{
    __shared__ short As[128 * 32];
    __shared__ short Bs[128 * 32];
    const int t = threadIdx.x;
    const int w = t >> 6, lane = t & 63;
    const int wr = w >> 1, wc = w & 1;
    const int rowBase = blockIdx.y * 128;
    const int colBase = blockIdx.x * 128;
    const int q = lane >> 4;        // quarter-wave 0..3
    const int r16 = lane & 15;

    f32x4 acc[4][4] = {};

    const int sRow = t >> 2;        // 0..63: row within 64-row staging round
    const int sOff = (t & 3) * 8;   // element offset within 32-elem row piece

    for (int k0 = 0; k0 < K; k0 += 32) {
        #pragma unroll
        for (int rr = 0; rr < 2; ++rr) {
            const unsigned short* gA = A + (size_t)(rowBase + rr * 64 + sRow) * K + k0 + sOff;
            load16_to_lds(gA, (char*)As + rr * 4096 + w * 1024);
            const unsigned short* gB = Bt + (size_t)(colBase + rr * 64 + sRow) * K + k0 + sOff;
            load16_to_lds(gB, (char*)Bs + rr * 4096 + w * 1024);
        }
        __syncthreads();

        short8 af[4], bfr[4];
        #pragma unroll
        for (int m = 0; m < 4; ++m)
            af[m] = *(const short8*)&As[(wr * 64 + m * 16 + r16) * 32 + q * 8];
        #pragma unroll
        for (int n = 0; n < 4; ++n)
            bfr[n] = *(const short8*)&Bs[(wc * 64 + n * 16 + r16) * 32 + q * 8];
        #pragma unroll
        for (int m = 0; m < 4; ++m)
            #pragma unroll
            for (int n = 0; n < 4; ++n)
                acc[m][n] = __builtin_amdgcn_mfma_f32_16x16x32_bf16(af[m], bfr[n], acc[m][n], 0, 0, 0);
        __syncthreads();
    }

    #pragma unroll
    for (int m = 0; m < 4; ++m) {
        #pragma unroll
        for (int r = 0; r < 4; ++r) {
            int gr = rowBase + wr * 64 + m * 16 + q * 4 + r;
            if (gr < M) {
                #pragma unroll
                for (int n = 0; n < 4; ++n)
                    C[(size_t)gr * N + colBase + wc * 64 + n * 16 + r16] = f2bf(acc[m][n][r]);
            }
        }
    }
}

// ---------------- alpha_s / alpha_d dots (bf16 h) ----------------

template <int H, int C>
__global__ __launch_bounds__(256) void alphas_kernel(const unsigned short* __restrict__ h,
                                                     const float* __restrict__ a_src,
                                                     const float* __restrict__ a_dst,
                                                     float* __restrict__ als,
                                                     float* __restrict__ ald,
                                                     int n_nodes) {
    constexpr int HC = H * C;
    constexpr int PER = HC / 64;
    constexpr int GRPL = 64 / H;
    const int wave = threadIdx.x >> 6;
    const int lane = threadIdx.x & 63;
    const int n = blockIdx.x * 4 + wave;
    if (n >= n_nodes) return;

    const unsigned short* hr = h + (size_t)n * HC + lane * PER;
    float hv[PER];
    if constexpr (PER == 8) {
        short8 v = *(const short8*)hr;
        #pragma unroll
        for (int j = 0; j < 8; ++j) hv[j] = bf2f((unsigned short)v[j]);
    } else {
        unsigned int v = *(const unsigned int*)hr;
        hv[0] = bf2f((unsigned short)(v & 0xFFFFu));
        hv[1] = bf2f((unsigned short)(v >> 16));
    }
    float s_acc = 0.f, d_acc = 0.f;
    #pragma unroll
    for (int j = 0; j < PER; ++j) {
        s_acc += hv[j] * a_src[lane * PER + j];
        d_acc += hv[j] * a_dst[lane * PER + j];
    }
    #pragma unroll
    for (int off = GRPL >> 1; off >= 1; off >>= 1) {
        s_acc += __shfl_xor(s_acc, off);
        d_acc += __shfl_xor(d_acc, off);
    }
    if ((lane % GRPL) == 0) {
        int head = lane / GRPL;
        als[(size_t)n * H + head] = s_acc;
        ald[(size_t)n * H + head] = d_acc;
    }
}

// ---------------- segment softmax + aggregate: one wave per node -----------

template <int H, int C, bool OUT_F32>
__global__ __launch_bounds__(256) void aggregate_kernel(
    const unsigned short* __restrict__ hfeat,   // [N, H*C] bf16
    const float* __restrict__ als, const float* __restrict__ ald,
    const int* __restrict__ row_ptr, const int* __restrict__ csr_src,
    const float* __restrict__ bias, void* __restrict__ outp, int n_nodes)
{
    constexpr int HC = H * C;
    constexpr int PER = HC / 64;      // channels per lane
    constexpr int GRPL = 64 / H;      // lanes per head
    const int lane = threadIdx.x & 63;
    const int wv = threadIdx.x >> 6;
    const int n = blockIdx.x * 4 + wv;
    if (n >= n_nodes) return;
    const int head = lane / GRPL;
    const int li = lane % GRPL;
    const int grpBase = lane & ~(GRPL - 1);

    const int start = row_ptr[n];
    const int deg = row_ptr[n + 1] - start;
    const float aldv = ald[(size_t)n * H + head];

    // phase 1: per-head max, exp-sum
    float mx = -INFINITY;
    for (int i = li; i < deg; i += GRPL) {
        int s = csr_src[start + i];
        float e = als[(size_t)s * H + head] + aldv;
        e = e > 0.f ? e : LRELU_SLOPE * e;
        mx = fmaxf(mx, e);
    }
    #pragma unroll
    for (int off = GRPL >> 1; off >= 1; off >>= 1) mx = fmaxf(mx, __shfl_xor(mx, off));
    float sum = 0.f;
    for (int i = li; i < deg; i += GRPL) {
        int s = csr_src[start + i];
        float e = als[(size_t)s * H + head] + aldv;
        e = e > 0.f ? e : LRELU_SLOPE * e;
        sum += __expf(e - mx);
    }
    #pragma unroll
    for (int off = GRPL >> 1; off >= 1; off >>= 1) sum += __shfl_xor(sum, off);
    const float scale = 1.f / (sum + 1e-16f);

    // phase 2: chunked gather-accumulate
    float acc[PER] = {};
    for (int base = 0; base < deg; base += GRPL) {
        const int cnt = min(GRPL, deg - base);
        int s_l = 0; float a_l = 0.f;
        if (li < cnt) {
            s_l = csr_src[start + base + li];
            float e = als[(size_t)s_l * H + head] + aldv;
            e = e > 0.f ? e : LRELU_SLOPE * e;
            a_l = __expf(e - mx) * scale;
        }
        for (int e = 0; e < cnt; ++e) {
            const int sl = grpBase + e;
            const int s = __shfl(s_l, sl);
            const float a = __shfl(a_l, sl);
            const unsigned short* row = hfeat + (size_t)s * HC + lane * PER;
            if constexpr (PER == 8) {
                short8 v = *(const short8*)row;
                #pragma unroll
                for (int j = 0; j < 8; ++j) acc[j] += a * bf2f((unsigned short)v[j]);
            } else {
                unsigned int v = *(const unsigned int*)row;
                acc[0] += a * bf2f((unsigned short)(v & 0xFFFFu));
                acc[1] += a * bf2f((unsigned short)(v >> 16));
            }
        }
    }

    // epilogue: + bias, ELU, store
    float ov[PER];
    #pragma unroll
    for (int j = 0; j < PER; ++j) {
        float o = acc[j] + bias[lane * PER + j];
        ov[j] = o > 0.f ? o : expm1f(o);
    }
    if constexpr (OUT_F32) {
        float* out = (float*)outp;
        #pragma unroll
        for (int j = 0; j < PER; ++j) out[(size_t)n * HC + lane * PER + j] = ov[j];
    } else {
        unsigned short* out = (unsigned short*)outp;
        if constexpr (PER == 8) {
            short8 v;
            #pragma unroll
            for (int j = 0; j < 8; ++j) v[j] = (short)f2bf(ov[j]);
            *(short8*)&out[(size_t)n * HC + lane * PER] = v;
        } else {
            unsigned int v = (unsigned int)f2bf(ov[0]) | ((unsigned int)f2bf(ov[1]) << 16);
            *(unsigned int*)&out[(size_t)n * HC + lane * PER] = v;
        }
    }
}

// ---------------------------------------------------------------------------

extern "C" void kernel_launch(void* const* d_in, const int* in_sizes, int n_in,
                              void* d_out, int out_size, void* d_ws, size_t ws_size,
                              hipStream_t stream) {
    const float* x   = (const float*)d_in[0];
    const int*   ei  = (const int*)d_in[1];
    const float* W1  = (const float*)d_in[2];
    const float* as1 = (const float*)d_in[3];
    const float* ad1 = (const float*)d_in[4];
    const float* b1  = (const float*)d_in[5];
    const float* W2  = (const float*)d_in[6];
    const float* as2 = (const float*)d_in[7];
    const float* ad2 = (const float*)d_in[8];
    const float* b2  = (const float*)d_in[9];
    const float* W3  = (const float*)d_in[10];
    const float* as3 = (const float*)d_in[11];
    const float* ad3 = (const float*)d_in[12];
    const float* b3  = (const float*)d_in[13];

    const int N = in_sizes[0] / 64;      // 50000
    const int E = in_sizes[1] / 2;       // 400000
    const int HC = 512;

    const int* src = ei;
    const int* dst = ei + E;

    size_t off = 0;
    auto carve = [&](size_t bytes) -> void* {
        void* p = (char*)d_ws + off;
        off += (bytes + 255) & ~(size_t)255;
        return p;
    };
    unsigned short* x_bf    = (unsigned short*)carve((size_t)MPAD * 64 * 2);
    unsigned short* feat_bf = (unsigned short*)carve((size_t)MPAD * HC * 2);
    unsigned short* h_bf    = (unsigned short*)carve((size_t)N * HC * 2);
    unsigned short* W1t     = (unsigned short*)carve((size_t)512 * 64 * 2);
    unsigned short* W2t     = (unsigned short*)carve((size_t)512 * 512 * 2);
    unsigned short* W3t     = (unsigned short*)carve((size_t)128 * 512 * 2);
    float* als    = (float*)carve((size_t)N * 4 * sizeof(float));
    float* ald    = (float*)carve((size_t)N * 4 * sizeof(float));
    int*   counts = (int*)carve((size_t)N * sizeof(int));
    int*   row_ptr= (int*)carve((size_t)(N + 1) * sizeof(int));
    int*   cursor = (int*)carve((size_t)N * sizeof(int));
    int*   csr_src= (int*)carve((size_t)E * sizeof(int));
    (void)ws_size;

    // ---- CSR build ----
    hipMemsetAsync(counts, 0, (size_t)N * sizeof(int), stream);
    count_deg_kernel<<<(E + 255) / 256, 256, 0, stream>>>(dst, counts, E);
    scan_kernel<<<1, 1024, 0, stream>>>(counts, row_ptr, N);
    init_cursor_kernel<<<(N + 255) / 256, 256, 0, stream>>>(row_ptr, cursor, N);
    fill_csr_kernel<<<(E + 255) / 256, 256, 0, stream>>>(src, dst, cursor, csr_src, E);

    // ---- casts ----
    cast_f32_bf16_kernel<<<((size_t)N * 64 + 255) / 256, 256, 0, stream>>>(x, x_bf, (size_t)N * 64);
    transpose_cast_kernel<<<(64 * 512 + 255) / 256, 256, 0, stream>>>(W1, W1t, 64, 512);
    transpose_cast_kernel<<<(512 * 512 + 255) / 256, 256, 0, stream>>>(W2, W2t, 512, 512);
    transpose_cast_kernel<<<(512 * 128 + 255) / 256, 256, 0, stream>>>(W3, W3t, 512, 128);

    const int rowTiles = (N + 127) / 128;   // 391
    const int aggBlocks = (N + 3) / 4;

    // ---- layer 1: x[N,64] @ W1 -> h[N,512] ----
    gemm_mfma_kernel<<<dim3(512 / 128, rowTiles), 256, 0, stream>>>(x_bf, W1t, h_bf, N, 512, 64);
    alphas_kernel<4, 128><<<aggBlocks, 256, 0, stream>>>(h_bf, as1, ad1, als, ald, N);
    aggregate_kernel<4, 128, false><<<aggBlocks, 256, 0, stream>>>(h_bf, als, ald, row_ptr,
                                                                   csr_src, b1, feat_bf, N);
    // ---- layer 2: feat[N,512] @ W2 -> h[N,512] ----
    gemm_mfma_kernel<<<dim3(512 / 128, rowTiles), 256, 0, stream>>>(feat_bf, W2t, h_bf, N, 512, 512);
    alphas_kernel<4, 128><<<aggBlocks, 256, 0, stream>>>(h_bf, as2, ad2, als, ald, N);
    aggregate_kernel<4, 128, false><<<aggBlocks, 256, 0, stream>>>(h_bf, als, ald, row_ptr,
                                                                   csr_src, b2, feat_bf, N);
    // ---- layer 3: feat[N,512] @ W3 -> h[N,128], single head ----
    gemm_mfma_kernel<<<dim3(128 / 128, rowTiles), 256, 0, stream>>>(feat_bf, W3t, h_bf, N, 128, 512);
    alphas_kernel<1, 128><<<aggBlocks, 256, 0, stream>>>(h_bf, as3, ad3, als, ald, N);
    aggregate_kernel<1, 128, true><<<aggBlocks, 256, 0, stream>>>(h_bf, als, ald, row_ptr,
                                                                  csr_src, b3, d_out, N);
}

// Round 3
// 438.043 us; speedup vs baseline: 2.2865x; 1.1375x over previous
//
#include <hip/hip_runtime.h>
#include <math.h>

// ---------------------------------------------------------------------------
// 3-layer GAT on MI355X — round 3:
//   * multi-block scan (was 94us single-block)
//   * single-pass aggregate (exp without max-sub; normalize at end)
//   * alpha dots fused into GEMM epilogue (alphas_kernel removed)
// ---------------------------------------------------------------------------

#define LRELU_SLOPE 0.2f
#define MPAD 50048              // 391 * 128, padded row count for GEMM A tiles

typedef __attribute__((ext_vector_type(8))) short short8;
typedef __attribute__((ext_vector_type(4))) float f32x4;

__device__ __forceinline__ float bf2f(unsigned short u) {
    return __uint_as_float(((unsigned int)u) << 16);
}
__device__ __forceinline__ unsigned short f2bf(float f) {
    unsigned int u = __float_as_uint(f);
    unsigned int r = u + 0x7FFFu + ((u >> 16) & 1u);   // RNE
    return (unsigned short)(r >> 16);
}
__device__ __forceinline__ void load16_to_lds(const void* g, void* l) {
    __builtin_amdgcn_global_load_lds(
        (const __attribute__((address_space(1))) void*)g,
        (__attribute__((address_space(3))) void*)l, 16, 0, 0);
}

// ---------------- CSR build ----------------

__global__ void count_deg_kernel(const int* __restrict__ dst, int* __restrict__ counts, int E) {
    int e = blockIdx.x * blockDim.x + threadIdx.x;
    if (e < E) atomicAdd(&counts[dst[e]], 1);
}

// pass 1: per-block (1024) inclusive scan; row_ptr[i+1] = block-local inclusive
__global__ __launch_bounds__(1024) void scan1_kernel(const int* __restrict__ counts,
                                                     int* __restrict__ row_ptr,
                                                     int* __restrict__ partial, int n) {
    __shared__ int wsum[16];
    const int t = threadIdx.x;
    const int lane = t & 63, w = t >> 6;
    const int i = blockIdx.x * 1024 + t;
    int v = (i < n) ? counts[i] : 0;
    int s = v;
    #pragma unroll
    for (int off = 1; off < 64; off <<= 1) {
        int u = __shfl_up(s, off);
        if (lane >= off) s += u;
    }
    if (lane == 63) wsum[w] = s;
    __syncthreads();
    if (w == 0 && lane < 16) {
        int tv = wsum[lane];
        #pragma unroll
        for (int off = 1; off < 16; off <<= 1) {
            int u = __shfl_up(tv, off);
            if (lane >= off) tv += u;
        }
        wsum[lane] = tv;
    }
    __syncthreads();
    int incl = s + (w > 0 ? wsum[w - 1] : 0);
    if (i < n) row_ptr[i + 1] = incl;
    if (t == 0) partial[blockIdx.x] = wsum[15];
}

// pass 2: one wave exclusive-scans the <=64 block totals in place
__global__ void scan2_kernel(int* __restrict__ partial, int nb) {
    int lane = threadIdx.x;
    int v = (lane < nb) ? partial[lane] : 0;
    int s = v;
    #pragma unroll
    for (int off = 1; off < 64; off <<= 1) {
        int u = __shfl_up(s, off);
        if (lane >= off) s += u;
    }
    if (lane < nb) partial[lane] = s - v;
}

// pass 3: add block offsets
__global__ __launch_bounds__(1024) void scan3_kernel(int* __restrict__ row_ptr,
                                                     const int* __restrict__ partial, int n) {
    const int i = blockIdx.x * 1024 + threadIdx.x;
    if (i < n) row_ptr[i + 1] += partial[blockIdx.x];
    if (i == 0) row_ptr[0] = 0;
}

__global__ void init_cursor_kernel(const int* __restrict__ row_ptr, int* __restrict__ cursor, int n) {
    int i = blockIdx.x * blockDim.x + threadIdx.x;
    if (i < n) cursor[i] = row_ptr[i];
}

__global__ void fill_csr_kernel(const int* __restrict__ src, const int* __restrict__ dst,
                                int* __restrict__ cursor, int* __restrict__ csr_src, int E) {
    int e = blockIdx.x * blockDim.x + threadIdx.x;
    if (e < E) {
        int d = dst[e];
        int pos = atomicAdd(&cursor[d], 1);
        csr_src[pos] = src[e];
    }
}

// ---------------- casts ----------------

__global__ void cast_f32_bf16_kernel(const float* __restrict__ in, unsigned short* __restrict__ out,
                                     size_t n) {
    size_t i = (size_t)blockIdx.x * blockDim.x + threadIdx.x;
    if (i < n) out[i] = f2bf(in[i]);
}

// W [K, Nw] fp32 row-major  ->  Wt [Nw, K] bf16 row-major
__global__ void transpose_cast_kernel(const float* __restrict__ W, unsigned short* __restrict__ Wt,
                                      int K, int Nw) {
    int i = blockIdx.x * blockDim.x + threadIdx.x;
    if (i < K * Nw) {
        int k = i / Nw, nn = i % Nw;
        Wt[(size_t)nn * K + k] = f2bf(W[i]);
    }
}

// ---------------- bf16 MFMA GEMM + fused alpha dots ------------------------
// C[M,N] = A[Mpad,K] @ Bt[N,K]^T.  128x128 tile, BK=32, 4 waves (2x2),
// each wave 64x64 (4x4 frags of 16x16x32).  Tile width 128 == C, so
// blockIdx.x is the head; epilogue reduces acc against a_src/a_dst and
// atomicAdds per-row partials into als/ald (exactly 2 contributors/row).

__global__ __launch_bounds__(256) void gemm_mfma_kernel(
    const unsigned short* __restrict__ A,    // [>=grid.y*128, K] bf16
    const unsigned short* __restrict__ Bt,   // [N, K] bf16
    unsigned short* __restrict__ C,          // [M, N] bf16
    const float* __restrict__ a_src,         // [H*C] == [N]
    const float* __restrict__ a_dst,
    float* __restrict__ als,                 // [M, H] (zeroed)
    float* __restrict__ ald,
    int M, int N, int K, int H)
{
    __shared__ short As[128 * 32];
    __shared__ short Bs[128 * 32];
    const int t = threadIdx.x;
    const int w = t >> 6, lane = t & 63;
    const int wr = w >> 1, wc = w & 1;
    const int rowBase = blockIdx.y * 128;
    const int colBase = blockIdx.x * 128;
    const int q = lane >> 4;        // quarter-wave 0..3
    const int r16 = lane & 15;

    f32x4 acc[4][4] = {};

    const int sRow = t >> 2;        // 0..63: row within 64-row staging round
    const int sOff = (t & 3) * 8;   // element offset within 32-elem row piece

    for (int k0 = 0; k0 < K; k0 += 32) {
        #pragma unroll
        for (int rr = 0; rr < 2; ++rr) {
            const unsigned short* gA = A + (size_t)(rowBase + rr * 64 + sRow) * K + k0 + sOff;
            load16_to_lds(gA, (char*)As + rr * 4096 + w * 1024);
            const unsigned short* gB = Bt + (size_t)(colBase + rr * 64 + sRow) * K + k0 + sOff;
            load16_to_lds(gB, (char*)Bs + rr * 4096 + w * 1024);
        }
        __syncthreads();

        short8 af[4], bfr[4];
        #pragma unroll
        for (int m = 0; m < 4; ++m)
            af[m] = *(const short8*)&As[(wr * 64 + m * 16 + r16) * 32 + q * 8];
        #pragma unroll
        for (int n = 0; n < 4; ++n)
            bfr[n] = *(const short8*)&Bs[(wc * 64 + n * 16 + r16) * 32 + q * 8];
        #pragma unroll
        for (int m = 0; m < 4; ++m)
            #pragma unroll
            for (int n = 0; n < 4; ++n)
                acc[m][n] = __builtin_amdgcn_mfma_f32_16x16x32_bf16(af[m], bfr[n], acc[m][n], 0, 0, 0);
        __syncthreads();
    }

    // per-column attention weights for this wave's 64-col slab
    float asv[4], adv[4];
    #pragma unroll
    for (int n = 0; n < 4; ++n) {
        int col = colBase + wc * 64 + n * 16 + r16;
        asv[n] = a_src[col];
        adv[n] = a_dst[col];
    }
    const int head = blockIdx.x;

    #pragma unroll
    for (int m = 0; m < 4; ++m) {
        #pragma unroll
        for (int r = 0; r < 4; ++r) {
            const int gr = rowBase + wr * 64 + m * 16 + q * 4 + r;
            float ps = 0.f, pd = 0.f;
            #pragma unroll
            for (int n = 0; n < 4; ++n) {
                ps += acc[m][n][r] * asv[n];
                pd += acc[m][n][r] * adv[n];
            }
            #pragma unroll
            for (int off = 8; off >= 1; off >>= 1) {
                ps += __shfl_xor(ps, off);
                pd += __shfl_xor(pd, off);
            }
            if (gr < M) {
                if (r16 == 0) {
                    atomicAdd(&als[(size_t)gr * H + head], ps);
                    atomicAdd(&ald[(size_t)gr * H + head], pd);
                }
                #pragma unroll
                for (int n = 0; n < 4; ++n)
                    C[(size_t)gr * N + colBase + wc * 64 + n * 16 + r16] = f2bf(acc[m][n][r]);
            }
        }
    }
}

// ---------------- single-pass segment softmax + aggregate ------------------
// One wave per node.  Unnormalized weights w = exp(leakyrelu(e)) (logits are
// O(10), safe in f32); normalize by the summed weight at the end.

template <int H, int C, bool OUT_F32>
__global__ __launch_bounds__(256) void aggregate_fused_kernel(
    const unsigned short* __restrict__ hfeat,   // [N, H*C] bf16
    const float* __restrict__ als, const float* __restrict__ ald,
    const int* __restrict__ row_ptr, const int* __restrict__ csr_src,
    const float* __restrict__ bias, void* __restrict__ outp, int n_nodes)
{
    constexpr int HC = H * C;
    constexpr int PER = HC / 64;      // channels per lane
    constexpr int GRPL = 64 / H;      // lanes per head
    const int lane = threadIdx.x & 63;
    const int wv = threadIdx.x >> 6;
    const int n = blockIdx.x * 4 + wv;
    if (n >= n_nodes) return;
    const int head = lane / GRPL;
    const int li = lane % GRPL;
    const int grpBase = lane & ~(GRPL - 1);

    const int start = row_ptr[n];
    const int deg = row_ptr[n + 1] - start;
    const float aldv = ald[(size_t)n * H + head];

    float acc[PER] = {};
    float wsum = 0.f;

    for (int base = 0; base < deg; base += GRPL) {
        const int cnt = min(GRPL, deg - base);
        int s_l = 0; float w_l = 0.f;
        if (li < cnt) {
            s_l = csr_src[start + base + li];
            float e = als[(size_t)s_l * H + head] + aldv;
            e = e > 0.f ? e : LRELU_SLOPE * e;
            w_l = __expf(e);
            wsum += w_l;
        }
        for (int e = 0; e < cnt; ++e) {
            const int sl = grpBase + e;
            const int s = __shfl(s_l, sl);
            const float a = __shfl(w_l, sl);
            const unsigned short* row = hfeat + (size_t)s * HC + lane * PER;
            if constexpr (PER == 8) {
                short8 v = *(const short8*)row;
                #pragma unroll
                for (int j = 0; j < 8; ++j) acc[j] += a * bf2f((unsigned short)v[j]);
            } else {
                unsigned int v = *(const unsigned int*)row;
                acc[0] += a * bf2f((unsigned short)(v & 0xFFFFu));
                acc[1] += a * bf2f((unsigned short)(v >> 16));
            }
        }
    }

    #pragma unroll
    for (int off = GRPL >> 1; off >= 1; off >>= 1) wsum += __shfl_xor(wsum, off);
    const float scale = (deg > 0) ? 1.f / wsum : 0.f;

    float ov[PER];
    #pragma unroll
    for (int j = 0; j < PER; ++j) {
        float o = acc[j] * scale + bias[lane * PER + j];
        ov[j] = o > 0.f ? o : expm1f(o);
    }
    if constexpr (OUT_F32) {
        float* out = (float*)outp;
        #pragma unroll
        for (int j = 0; j < PER; ++j) out[(size_t)n * HC + lane * PER + j] = ov[j];
    } else {
        unsigned short* out = (unsigned short*)outp;
        if constexpr (PER == 8) {
            short8 v;
            #pragma unroll
            for (int j = 0; j < 8; ++j) v[j] = (short)f2bf(ov[j]);
            *(short8*)&out[(size_t)n * HC + lane * PER] = v;
        } else {
            unsigned int v = (unsigned int)f2bf(ov[0]) | ((unsigned int)f2bf(ov[1]) << 16);
            *(unsigned int*)&out[(size_t)n * HC + lane * PER] = v;
        }
    }
}

// ---------------------------------------------------------------------------

extern "C" void kernel_launch(void* const* d_in, const int* in_sizes, int n_in,
                              void* d_out, int out_size, void* d_ws, size_t ws_size,
                              hipStream_t stream) {
    const float* x   = (const float*)d_in[0];
    const int*   ei  = (const int*)d_in[1];
    const float* W1  = (const float*)d_in[2];
    const float* as1 = (const float*)d_in[3];
    const float* ad1 = (const float*)d_in[4];
    const float* b1  = (const float*)d_in[5];
    const float* W2  = (const float*)d_in[6];
    const float* as2 = (const float*)d_in[7];
    const float* ad2 = (const float*)d_in[8];
    const float* b2  = (const float*)d_in[9];
    const float* W3  = (const float*)d_in[10];
    const float* as3 = (const float*)d_in[11];
    const float* ad3 = (const float*)d_in[12];
    const float* b3  = (const float*)d_in[13];

    const int N = in_sizes[0] / 64;      // 50000
    const int E = in_sizes[1] / 2;       // 400000
    const int HC = 512;

    const int* src = ei;
    const int* dst = ei + E;

    size_t off = 0;
    auto carve = [&](size_t bytes) -> void* {
        void* p = (char*)d_ws + off;
        off += (bytes + 255) & ~(size_t)255;
        return p;
    };
    unsigned short* x_bf    = (unsigned short*)carve((size_t)MPAD * 64 * 2);
    unsigned short* feat_bf = (unsigned short*)carve((size_t)MPAD * HC * 2);
    unsigned short* h_bf    = (unsigned short*)carve((size_t)N * HC * 2);
    unsigned short* W1t     = (unsigned short*)carve((size_t)512 * 64 * 2);
    unsigned short* W2t     = (unsigned short*)carve((size_t)512 * 512 * 2);
    unsigned short* W3t     = (unsigned short*)carve((size_t)128 * 512 * 2);
    float* alsald = (float*)carve((size_t)N * 4 * 2 * sizeof(float));
    float* als    = alsald;
    float* ald    = alsald + (size_t)N * 4;
    int*   counts = (int*)carve((size_t)N * sizeof(int));
    int*   row_ptr= (int*)carve((size_t)(N + 1) * sizeof(int));
    int*   cursor = (int*)carve((size_t)N * sizeof(int));
    int*   csr_src= (int*)carve((size_t)E * sizeof(int));
    int*   partial= (int*)carve(64 * sizeof(int));
    (void)ws_size;

    const int nb = (N + 1023) / 1024;    // scan blocks (49 <= 64)

    // ---- CSR build ----
    hipMemsetAsync(counts, 0, (size_t)N * sizeof(int), stream);
    count_deg_kernel<<<(E + 255) / 256, 256, 0, stream>>>(dst, counts, E);
    scan1_kernel<<<nb, 1024, 0, stream>>>(counts, row_ptr, partial, N);
    scan2_kernel<<<1, 64, 0, stream>>>(partial, nb);
    scan3_kernel<<<nb, 1024, 0, stream>>>(row_ptr, partial, N);
    init_cursor_kernel<<<(N + 255) / 256, 256, 0, stream>>>(row_ptr, cursor, N);
    fill_csr_kernel<<<(E + 255) / 256, 256, 0, stream>>>(src, dst, cursor, csr_src, E);

    // ---- casts ----
    cast_f32_bf16_kernel<<<((size_t)N * 64 + 255) / 256, 256, 0, stream>>>(x, x_bf, (size_t)N * 64);
    transpose_cast_kernel<<<(64 * 512 + 255) / 256, 256, 0, stream>>>(W1, W1t, 64, 512);
    transpose_cast_kernel<<<(512 * 512 + 255) / 256, 256, 0, stream>>>(W2, W2t, 512, 512);
    transpose_cast_kernel<<<(512 * 128 + 255) / 256, 256, 0, stream>>>(W3, W3t, 512, 128);

    const int rowTiles = (N + 127) / 128;   // 391
    const int aggBlocks = (N + 3) / 4;
    const size_t alsBytes = (size_t)N * 4 * 2 * sizeof(float);

    // ---- layer 1: x[N,64] @ W1 -> h[N,512] ----
    hipMemsetAsync(alsald, 0, alsBytes, stream);
    gemm_mfma_kernel<<<dim3(4, rowTiles), 256, 0, stream>>>(x_bf, W1t, h_bf, as1, ad1,
                                                            als, ald, N, 512, 64, 4);
    aggregate_fused_kernel<4, 128, false><<<aggBlocks, 256, 0, stream>>>(
        h_bf, als, ald, row_ptr, csr_src, b1, feat_bf, N);

    // ---- layer 2: feat[N,512] @ W2 -> h[N,512] ----
    hipMemsetAsync(alsald, 0, alsBytes, stream);
    gemm_mfma_kernel<<<dim3(4, rowTiles), 256, 0, stream>>>(feat_bf, W2t, h_bf, as2, ad2,
                                                            als, ald, N, 512, 512, 4);
    aggregate_fused_kernel<4, 128, false><<<aggBlocks, 256, 0, stream>>>(
        h_bf, als, ald, row_ptr, csr_src, b2, feat_bf, N);

    // ---- layer 3: feat[N,512] @ W3 -> h[N,128], single head ----
    hipMemsetAsync(alsald, 0, alsBytes, stream);
    gemm_mfma_kernel<<<dim3(1, rowTiles), 256, 0, stream>>>(feat_bf, W3t, h_bf, as3, ad3,
                                                            als, ald, N, 128, 512, 1);
    aggregate_fused_kernel<1, 128, true><<<aggBlocks, 256, 0, stream>>>(
        h_bf, als, ald, row_ptr, csr_src, b3, d_out, N);
}

// Round 4
// 434.720 us; speedup vs baseline: 2.3040x; 1.0076x over previous
//
#include <hip/hip_runtime.h>
#include <math.h>

// ---------------------------------------------------------------------------
// 3-layer GAT on MI355X — round 4:
//   * GEMM LDS XOR-swizzle via pre-swizzled global source (rule #21):
//     kills the 8-way ds_read_b128 bank conflict (3.2M -> ~0)
//   * aggregate gather loop unrolled x4 (4 row-loads in flight)
// ---------------------------------------------------------------------------

#define LRELU_SLOPE 0.2f
#define MPAD 50048              // 391 * 128, padded row count for GEMM A tiles

typedef __attribute__((ext_vector_type(8))) short short8;
typedef __attribute__((ext_vector_type(4))) float f32x4;

__device__ __forceinline__ float bf2f(unsigned short u) {
    return __uint_as_float(((unsigned int)u) << 16);
}
__device__ __forceinline__ unsigned short f2bf(float f) {
    unsigned int u = __float_as_uint(f);
    unsigned int r = u + 0x7FFFu + ((u >> 16) & 1u);   // RNE
    return (unsigned short)(r >> 16);
}
__device__ __forceinline__ void load16_to_lds(const void* g, void* l) {
    __builtin_amdgcn_global_load_lds(
        (const __attribute__((address_space(1))) void*)g,
        (__attribute__((address_space(3))) void*)l, 16, 0, 0);
}

// ---------------- CSR build ----------------

__global__ void count_deg_kernel(const int* __restrict__ dst, int* __restrict__ counts, int E) {
    int e = blockIdx.x * blockDim.x + threadIdx.x;
    if (e < E) atomicAdd(&counts[dst[e]], 1);
}

__global__ __launch_bounds__(1024) void scan1_kernel(const int* __restrict__ counts,
                                                     int* __restrict__ row_ptr,
                                                     int* __restrict__ partial, int n) {
    __shared__ int wsum[16];
    const int t = threadIdx.x;
    const int lane = t & 63, w = t >> 6;
    const int i = blockIdx.x * 1024 + t;
    int v = (i < n) ? counts[i] : 0;
    int s = v;
    #pragma unroll
    for (int off = 1; off < 64; off <<= 1) {
        int u = __shfl_up(s, off);
        if (lane >= off) s += u;
    }
    if (lane == 63) wsum[w] = s;
    __syncthreads();
    if (w == 0 && lane < 16) {
        int tv = wsum[lane];
        #pragma unroll
        for (int off = 1; off < 16; off <<= 1) {
            int u = __shfl_up(tv, off);
            if (lane >= off) tv += u;
        }
        wsum[lane] = tv;
    }
    __syncthreads();
    int incl = s + (w > 0 ? wsum[w - 1] : 0);
    if (i < n) row_ptr[i + 1] = incl;
    if (t == 0) partial[blockIdx.x] = wsum[15];
}

__global__ void scan2_kernel(int* __restrict__ partial, int nb) {
    int lane = threadIdx.x;
    int v = (lane < nb) ? partial[lane] : 0;
    int s = v;
    #pragma unroll
    for (int off = 1; off < 64; off <<= 1) {
        int u = __shfl_up(s, off);
        if (lane >= off) s += u;
    }
    if (lane < nb) partial[lane] = s - v;
}

__global__ __launch_bounds__(1024) void scan3_kernel(int* __restrict__ row_ptr,
                                                     const int* __restrict__ partial, int n) {
    const int i = blockIdx.x * 1024 + threadIdx.x;
    if (i < n) row_ptr[i + 1] += partial[blockIdx.x];
    if (i == 0) row_ptr[0] = 0;
}

__global__ void init_cursor_kernel(const int* __restrict__ row_ptr, int* __restrict__ cursor, int n) {
    int i = blockIdx.x * blockDim.x + threadIdx.x;
    if (i < n) cursor[i] = row_ptr[i];
}

__global__ void fill_csr_kernel(const int* __restrict__ src, const int* __restrict__ dst,
                                int* __restrict__ cursor, int* __restrict__ csr_src, int E) {
    int e = blockIdx.x * blockDim.x + threadIdx.x;
    if (e < E) {
        int d = dst[e];
        int pos = atomicAdd(&cursor[d], 1);
        csr_src[pos] = src[e];
    }
}

// ---------------- casts ----------------

__global__ void cast_f32_bf16_kernel(const float* __restrict__ in, unsigned short* __restrict__ out,
                                     size_t n) {
    size_t i = (size_t)blockIdx.x * blockDim.x + threadIdx.x;
    if (i < n) out[i] = f2bf(in[i]);
}

__global__ void transpose_cast_kernel(const float* __restrict__ W, unsigned short* __restrict__ Wt,
                                      int K, int Nw) {
    int i = blockIdx.x * blockDim.x + threadIdx.x;
    if (i < K * Nw) {
        int k = i / Nw, nn = i % Nw;
        Wt[(size_t)nn * K + k] = f2bf(W[i]);
    }
}

// ---------------- bf16 MFMA GEMM + fused alpha dots ------------------------
// C[M,N] = A[Mpad,K] @ Bt[N,K]^T.  128x128 tile, BK=32, 4 waves (2x2).
// LDS tiles are [128 rows][32 shorts]; the 16B slot within each 64B row is
// XOR-swizzled by ((row>>1)&3).  global_load_lds writes LINEARLY, so the
// swizzle is applied by permuting the per-lane GLOBAL source slot (involution)
// and using the same XOR on the ds_read address (guide rule #21).

__global__ __launch_bounds__(256) void gemm_mfma_kernel(
    const unsigned short* __restrict__ A,    // [>=grid.y*128, K] bf16
    const unsigned short* __restrict__ Bt,   // [N, K] bf16
    unsigned short* __restrict__ C,          // [M, N] bf16
    const float* __restrict__ a_src,         // [H*C]
    const float* __restrict__ a_dst,
    float* __restrict__ als,                 // [M, H] (zeroed)
    float* __restrict__ ald,
    int M, int N, int K, int H)
{
    __shared__ short As[128 * 32];
    __shared__ short Bs[128 * 32];
    const int t = threadIdx.x;
    const int w = t >> 6, lane = t & 63;
    const int wr = w >> 1, wc = w & 1;
    const int rowBase = blockIdx.y * 128;
    const int colBase = blockIdx.x * 128;
    const int q = lane >> 4;        // quarter-wave 0..3 (K slot)
    const int r16 = lane & 15;
    const int qs = (q ^ ((r16 >> 1) & 3)) * 8;   // swizzled K-slot offset (shorts)

    f32x4 acc[4][4] = {};

    const int sRow = t >> 2;                               // 0..63 staging row
    const int sOff = ((t & 3) ^ ((sRow >> 1) & 3)) * 8;    // pre-swizzled global slot

    for (int k0 = 0; k0 < K; k0 += 32) {
        #pragma unroll
        for (int rr = 0; rr < 2; ++rr) {
            const unsigned short* gA = A + (size_t)(rowBase + rr * 64 + sRow) * K + k0 + sOff;
            load16_to_lds(gA, (char*)As + rr * 4096 + w * 1024);
            const unsigned short* gB = Bt + (size_t)(colBase + rr * 64 + sRow) * K + k0 + sOff;
            load16_to_lds(gB, (char*)Bs + rr * 4096 + w * 1024);
        }
        __syncthreads();

        short8 af[4], bfr[4];
        #pragma unroll
        for (int m = 0; m < 4; ++m)
            af[m] = *(const short8*)&As[(wr * 64 + m * 16 + r16) * 32 + qs];
        #pragma unroll
        for (int n = 0; n < 4; ++n)
            bfr[n] = *(const short8*)&Bs[(wc * 64 + n * 16 + r16) * 32 + qs];
        #pragma unroll
        for (int m = 0; m < 4; ++m)
            #pragma unroll
            for (int n = 0; n < 4; ++n)
                acc[m][n] = __builtin_amdgcn_mfma_f32_16x16x32_bf16(af[m], bfr[n], acc[m][n], 0, 0, 0);
        __syncthreads();
    }

    float asv[4], adv[4];
    #pragma unroll
    for (int n = 0; n < 4; ++n) {
        int col = colBase + wc * 64 + n * 16 + r16;
        asv[n] = a_src[col];
        adv[n] = a_dst[col];
    }
    const int head = blockIdx.x;

    #pragma unroll
    for (int m = 0; m < 4; ++m) {
        #pragma unroll
        for (int r = 0; r < 4; ++r) {
            const int gr = rowBase + wr * 64 + m * 16 + q * 4 + r;
            float ps = 0.f, pd = 0.f;
            #pragma unroll
            for (int n = 0; n < 4; ++n) {
                ps += acc[m][n][r] * asv[n];
                pd += acc[m][n][r] * adv[n];
            }
            #pragma unroll
            for (int off = 8; off >= 1; off >>= 1) {
                ps += __shfl_xor(ps, off);
                pd += __shfl_xor(pd, off);
            }
            if (gr < M) {
                if (r16 == 0) {
                    atomicAdd(&als[(size_t)gr * H + head], ps);
                    atomicAdd(&ald[(size_t)gr * H + head], pd);
                }
                #pragma unroll
                for (int n = 0; n < 4; ++n)
                    C[(size_t)gr * N + colBase + wc * 64 + n * 16 + r16] = f2bf(acc[m][n][r]);
            }
        }
    }
}

// ---------------- single-pass segment softmax + aggregate ------------------
// One wave per node; unnormalized w = exp(leakyrelu(e)); normalize at end.
// Gather loop unrolled x4 for memory-level parallelism.

template <int H, int C, bool OUT_F32>
__global__ __launch_bounds__(256) void aggregate_fused_kernel(
    const unsigned short* __restrict__ hfeat,   // [N, H*C] bf16
    const float* __restrict__ als, const float* __restrict__ ald,
    const int* __restrict__ row_ptr, const int* __restrict__ csr_src,
    const float* __restrict__ bias, void* __restrict__ outp, int n_nodes)
{
    constexpr int HC = H * C;
    constexpr int PER = HC / 64;      // channels per lane
    constexpr int GRPL = 64 / H;      // lanes per head
    const int lane = threadIdx.x & 63;
    const int wv = threadIdx.x >> 6;
    const int n = blockIdx.x * 4 + wv;
    if (n >= n_nodes) return;
    const int head = lane / GRPL;
    const int li = lane % GRPL;
    const int grpBase = lane & ~(GRPL - 1);

    const int start = row_ptr[n];
    const int deg = row_ptr[n + 1] - start;
    const float aldv = ald[(size_t)n * H + head];

    float acc[PER] = {};
    float wsum = 0.f;

    for (int base = 0; base < deg; base += GRPL) {
        const int cnt = min(GRPL, deg - base);
        int s_l = 0; float w_l = 0.f;
        if (li < cnt) {
            s_l = csr_src[start + base + li];
            float e = als[(size_t)s_l * H + head] + aldv;
            e = e > 0.f ? e : LRELU_SLOPE * e;
            w_l = __expf(e);
            wsum += w_l;
        }
        int e = 0;
        if constexpr (PER == 8) {
            for (; e + 4 <= cnt; e += 4) {
                const int s0 = __shfl(s_l, grpBase + e);
                const int s1 = __shfl(s_l, grpBase + e + 1);
                const int s2 = __shfl(s_l, grpBase + e + 2);
                const int s3 = __shfl(s_l, grpBase + e + 3);
                const float a0 = __shfl(w_l, grpBase + e);
                const float a1 = __shfl(w_l, grpBase + e + 1);
                const float a2 = __shfl(w_l, grpBase + e + 2);
                const float a3 = __shfl(w_l, grpBase + e + 3);
                short8 v0 = *(const short8*)(hfeat + (size_t)s0 * HC + lane * PER);
                short8 v1 = *(const short8*)(hfeat + (size_t)s1 * HC + lane * PER);
                short8 v2 = *(const short8*)(hfeat + (size_t)s2 * HC + lane * PER);
                short8 v3 = *(const short8*)(hfeat + (size_t)s3 * HC + lane * PER);
                #pragma unroll
                for (int j = 0; j < 8; ++j) {
                    acc[j] += a0 * bf2f((unsigned short)v0[j]);
                    acc[j] += a1 * bf2f((unsigned short)v1[j]);
                    acc[j] += a2 * bf2f((unsigned short)v2[j]);
                    acc[j] += a3 * bf2f((unsigned short)v3[j]);
                }
            }
            for (; e < cnt; ++e) {
                const int s = __shfl(s_l, grpBase + e);
                const float a = __shfl(w_l, grpBase + e);
                short8 v = *(const short8*)(hfeat + (size_t)s * HC + lane * PER);
                #pragma unroll
                for (int j = 0; j < 8; ++j) acc[j] += a * bf2f((unsigned short)v[j]);
            }
        } else {
            for (; e + 4 <= cnt; e += 4) {
                const int s0 = __shfl(s_l, grpBase + e);
                const int s1 = __shfl(s_l, grpBase + e + 1);
                const int s2 = __shfl(s_l, grpBase + e + 2);
                const int s3 = __shfl(s_l, grpBase + e + 3);
                const float a0 = __shfl(w_l, grpBase + e);
                const float a1 = __shfl(w_l, grpBase + e + 1);
                const float a2 = __shfl(w_l, grpBase + e + 2);
                const float a3 = __shfl(w_l, grpBase + e + 3);
                unsigned int v0 = *(const unsigned int*)(hfeat + (size_t)s0 * HC + lane * PER);
                unsigned int v1 = *(const unsigned int*)(hfeat + (size_t)s1 * HC + lane * PER);
                unsigned int v2 = *(const unsigned int*)(hfeat + (size_t)s2 * HC + lane * PER);
                unsigned int v3 = *(const unsigned int*)(hfeat + (size_t)s3 * HC + lane * PER);
                acc[0] += a0 * bf2f((unsigned short)(v0 & 0xFFFFu));
                acc[1] += a0 * bf2f((unsigned short)(v0 >> 16));
                acc[0] += a1 * bf2f((unsigned short)(v1 & 0xFFFFu));
                acc[1] += a1 * bf2f((unsigned short)(v1 >> 16));
                acc[0] += a2 * bf2f((unsigned short)(v2 & 0xFFFFu));
                acc[1] += a2 * bf2f((unsigned short)(v2 >> 16));
                acc[0] += a3 * bf2f((unsigned short)(v3 & 0xFFFFu));
                acc[1] += a3 * bf2f((unsigned short)(v3 >> 16));
            }
            for (; e < cnt; ++e) {
                const int s = __shfl(s_l, grpBase + e);
                const float a = __shfl(w_l, grpBase + e);
                unsigned int v = *(const unsigned int*)(hfeat + (size_t)s * HC + lane * PER);
                acc[0] += a * bf2f((unsigned short)(v & 0xFFFFu));
                acc[1] += a * bf2f((unsigned short)(v >> 16));
            }
        }
    }

    #pragma unroll
    for (int off = GRPL >> 1; off >= 1; off >>= 1) wsum += __shfl_xor(wsum, off);
    const float scale = (deg > 0) ? 1.f / wsum : 0.f;

    float ov[PER];
    #pragma unroll
    for (int j = 0; j < PER; ++j) {
        float o = acc[j] * scale + bias[lane * PER + j];
        ov[j] = o > 0.f ? o : expm1f(o);
    }
    if constexpr (OUT_F32) {
        float* out = (float*)outp;
        #pragma unroll
        for (int j = 0; j < PER; ++j) out[(size_t)n * HC + lane * PER + j] = ov[j];
    } else {
        unsigned short* out = (unsigned short*)outp;
        if constexpr (PER == 8) {
            short8 v;
            #pragma unroll
            for (int j = 0; j < 8; ++j) v[j] = (short)f2bf(ov[j]);
            *(short8*)&out[(size_t)n * HC + lane * PER] = v;
        } else {
            unsigned int v = (unsigned int)f2bf(ov[0]) | ((unsigned int)f2bf(ov[1]) << 16);
            *(unsigned int*)&out[(size_t)n * HC + lane * PER] = v;
        }
    }
}

// ---------------------------------------------------------------------------

extern "C" void kernel_launch(void* const* d_in, const int* in_sizes, int n_in,
                              void* d_out, int out_size, void* d_ws, size_t ws_size,
                              hipStream_t stream) {
    const float* x   = (const float*)d_in[0];
    const int*   ei  = (const int*)d_in[1];
    const float* W1  = (const float*)d_in[2];
    const float* as1 = (const float*)d_in[3];
    const float* ad1 = (const float*)d_in[4];
    const float* b1  = (const float*)d_in[5];
    const float* W2  = (const float*)d_in[6];
    const float* as2 = (const float*)d_in[7];
    const float* ad2 = (const float*)d_in[8];
    const float* b2  = (const float*)d_in[9];
    const float* W3  = (const float*)d_in[10];
    const float* as3 = (const float*)d_in[11];
    const float* ad3 = (const float*)d_in[12];
    const float* b3  = (const float*)d_in[13];

    const int N = in_sizes[0] / 64;      // 50000
    const int E = in_sizes[1] / 2;       // 400000
    const int HC = 512;

    const int* src = ei;
    const int* dst = ei + E;

    size_t off = 0;
    auto carve = [&](size_t bytes) -> void* {
        void* p = (char*)d_ws + off;
        off += (bytes + 255) & ~(size_t)255;
        return p;
    };
    unsigned short* x_bf    = (unsigned short*)carve((size_t)MPAD * 64 * 2);
    unsigned short* feat_bf = (unsigned short*)carve((size_t)MPAD * HC * 2);
    unsigned short* h_bf    = (unsigned short*)carve((size_t)N * HC * 2);
    unsigned short* W1t     = (unsigned short*)carve((size_t)512 * 64 * 2);
    unsigned short* W2t     = (unsigned short*)carve((size_t)512 * 512 * 2);
    unsigned short* W3t     = (unsigned short*)carve((size_t)128 * 512 * 2);
    float* alsald = (float*)carve((size_t)N * 4 * 2 * sizeof(float));
    float* als    = alsald;
    float* ald    = alsald + (size_t)N * 4;
    int*   counts = (int*)carve((size_t)N * sizeof(int));
    int*   row_ptr= (int*)carve((size_t)(N + 1) * sizeof(int));
    int*   cursor = (int*)carve((size_t)N * sizeof(int));
    int*   csr_src= (int*)carve((size_t)E * sizeof(int));
    int*   partial= (int*)carve(64 * sizeof(int));
    (void)ws_size;

    const int nb = (N + 1023) / 1024;    // 49 <= 64

    // ---- CSR build ----
    hipMemsetAsync(counts, 0, (size_t)N * sizeof(int), stream);
    count_deg_kernel<<<(E + 255) / 256, 256, 0, stream>>>(dst, counts, E);
    scan1_kernel<<<nb, 1024, 0, stream>>>(counts, row_ptr, partial, N);
    scan2_kernel<<<1, 64, 0, stream>>>(partial, nb);
    scan3_kernel<<<nb, 1024, 0, stream>>>(row_ptr, partial, N);
    init_cursor_kernel<<<(N + 255) / 256, 256, 0, stream>>>(row_ptr, cursor, N);
    fill_csr_kernel<<<(E + 255) / 256, 256, 0, stream>>>(src, dst, cursor, csr_src, E);

    // ---- casts ----
    cast_f32_bf16_kernel<<<((size_t)N * 64 + 255) / 256, 256, 0, stream>>>(x, x_bf, (size_t)N * 64);
    transpose_cast_kernel<<<(64 * 512 + 255) / 256, 256, 0, stream>>>(W1, W1t, 64, 512);
    transpose_cast_kernel<<<(512 * 512 + 255) / 256, 256, 0, stream>>>(W2, W2t, 512, 512);
    transpose_cast_kernel<<<(512 * 128 + 255) / 256, 256, 0, stream>>>(W3, W3t, 512, 128);

    const int rowTiles = (N + 127) / 128;   // 391
    const int aggBlocks = (N + 3) / 4;
    const size_t alsBytes = (size_t)N * 4 * 2 * sizeof(float);

    // ---- layer 1 ----
    hipMemsetAsync(alsald, 0, alsBytes, stream);
    gemm_mfma_kernel<<<dim3(4, rowTiles), 256, 0, stream>>>(x_bf, W1t, h_bf, as1, ad1,
                                                            als, ald, N, 512, 64, 4);
    aggregate_fused_kernel<4, 128, false><<<aggBlocks, 256, 0, stream>>>(
        h_bf, als, ald, row_ptr, csr_src, b1, feat_bf, N);

    // ---- layer 2 ----
    hipMemsetAsync(alsald, 0, alsBytes, stream);
    gemm_mfma_kernel<<<dim3(4, rowTiles), 256, 0, stream>>>(feat_bf, W2t, h_bf, as2, ad2,
                                                            als, ald, N, 512, 512, 4);
    aggregate_fused_kernel<4, 128, false><<<aggBlocks, 256, 0, stream>>>(
        h_bf, als, ald, row_ptr, csr_src, b2, feat_bf, N);

    // ---- layer 3 ----
    hipMemsetAsync(alsald, 0, alsBytes, stream);
    gemm_mfma_kernel<<<dim3(1, rowTiles), 256, 0, stream>>>(feat_bf, W3t, h_bf, as3, ad3,
                                                            als, ald, N, 128, 512, 1);
    aggregate_fused_kernel<1, 128, true><<<aggBlocks, 256, 0, stream>>>(
        h_bf, als, ald, row_ptr, csr_src, b3, d_out, N);
}